// Round 13
// baseline (134.906 us; speedup 1.0000x reference)
//
#include <hip/hip_runtime.h>
#include <math.h>

#define EPSV 1e-5f

typedef short bfx8 __attribute__((ext_vector_type(8)));
typedef float fx4  __attribute__((ext_vector_type(4)));

// cos/sin(2*pi*j/32)
constexpr float COS32[32] = {
     1.00000000f,  0.98078528f,  0.92387953f,  0.83146961f,
     0.70710678f,  0.55557023f,  0.38268343f,  0.19509032f,
     0.00000000f, -0.19509032f, -0.38268343f, -0.55557023f,
    -0.70710678f, -0.83146961f, -0.92387953f, -0.98078528f,
    -1.00000000f, -0.98078528f, -0.92387953f, -0.83146961f,
    -0.70710678f, -0.55557023f, -0.38268343f, -0.19509032f,
     0.00000000f,  0.19509032f,  0.38268343f,  0.55557023f,
     0.70710678f,  0.83146961f,  0.92387953f,  0.98078528f };
constexpr float SIN32X[32] = {
     0.00000000f,  0.19509032f,  0.38268343f,  0.55557023f,
     0.70710678f,  0.83146961f,  0.92387953f,  0.98078528f,
     1.00000000f,  0.98078528f,  0.92387953f,  0.83146961f,
     0.70710678f,  0.55557023f,  0.38268343f,  0.19509032f,
     0.00000000f, -0.19509032f, -0.38268343f, -0.55557023f,
    -0.70710678f, -0.83146961f, -0.92387953f, -0.98078528f,
    -1.00000000f, -0.98078528f, -0.92387953f, -0.83146961f,
    -0.70710678f, -0.55557023f, -0.38268343f, -0.19509032f };

__device__ __forceinline__ short f2bf(float f) {
    unsigned u = __float_as_uint(f);
    u += 0x7fffu + ((u >> 16) & 1u);
    return (short)(u >> 16);
}
__device__ __forceinline__ unsigned pk2bf(float a, float b) {
    return (unsigned)(unsigned short)f2bf(a) | ((unsigned)(unsigned short)f2bf(b) << 16);
}
__device__ __forceinline__ float bf2f(unsigned short h) {
    return __uint_as_float(((unsigned)h) << 16);
}
__device__ __forceinline__ float geluf(float x) {
    float x2 = x * x;
    float u2 = x * fmaf(0.0713548162726f, x2, 1.59576912161f);
    float e  = __expf(-u2);
    return x * __builtin_amdgcn_rcpf(1.f + e);
}

// ---------------- Kernel A: time-LN + scan + fused space-LN. (round-11 exact)
__global__ __launch_bounds__(256) void k_time_scan(
    const float* __restrict__ x, const float* __restrict__ dt,
    const float* __restrict__ lng, const float* __restrict__ lnb,
    const float* __restrict__ om, const float* __restrict__ bin,
    const float* __restrict__ hcr, const float* __restrict__ hci,
    const float* __restrict__ hd,
    const float* __restrict__ lnsg, const float* __restrict__ lnsb,
    unsigned short* __restrict__ buf1b, unsigned short* __restrict__ xnb,
    float* __restrict__ hout)
{
    const int wv = threadIdx.x >> 6, lane = threadIdx.x & 63;
    const int bhw = blockIdx.x * 4 + wv;
    const int b = bhw >> 10, hw = bhw & 1023;
    const int d = lane << 1;
    const float2 gd = *(const float2*)(lng + d);
    const float2 bd = *(const float2*)(lnb + d);
    const float2 omv = *(const float2*)(om + d);
    const float2 biv = *(const float2*)(bin + d);
    const float2 crv = *(const float2*)(hcr + d);
    const float2 civ = *(const float2*)(hci + d);
    const float2 dhv = *(const float2*)(hd + d);
    const float2 sgv = *(const float2*)(lnsg + d);
    const float2 sbv = *(const float2*)(lnsb + d);
    const size_t base = (size_t)b * 2097152 + (size_t)hw * 128;
    float2 xv[16]; float dts[16];
    #pragma unroll
    for (int t = 0; t < 16; ++t) {
        xv[t] = *(const float2*)(x + base + (size_t)t * 131072 + d);
        dts[t] = dt[b * 16 + t];
    }
    float hr0 = 0.f, hi0 = 0.f, hr1 = 0.f, hi1 = 0.f;
    #pragma unroll
    for (int t = 0; t < 16; ++t) {
        const float a0 = xv[t].x, a1 = xv[t].y;
        float s1 = a0 + a1;
        float s2 = a0 * a0 + a1 * a1;
        #pragma unroll
        for (int o = 32; o > 0; o >>= 1) {
            s1 += __shfl_xor(s1, o);
            s2 += __shfl_xor(s2, o);
        }
        const float mu = s1 * (1.f / 128.f);
        const float rv = rsqrtf(s2 * (1.f / 128.f) - mu * mu + EPSV);
        const float xt0 = (a0 - mu) * rv * gd.x + bd.x;
        const float xt1 = (a1 - mu) * rv * gd.y + bd.y;
        float sp0, cp0, sp1, cp1;
        __sincosf(omv.x * dts[t], &sp0, &cp0);
        __sincosf(omv.y * dts[t], &sp1, &cp1);
        float nhr = cp0 * hr0 - sp0 * hi0 + biv.x * xt0;
        float nhi = cp0 * hi0 + sp0 * hr0;
        hr0 = nhr; hi0 = nhi;
        nhr = cp1 * hr1 - sp1 * hi1 + biv.y * xt1;
        nhi = cp1 * hi1 + sp1 * hr1;
        hr1 = nhr; hi1 = nhi;
        const float bv0 = crv.x * hr0 - civ.x * hi0 + dhv.x * xt0 + a0;
        const float bv1 = crv.y * hr1 - civ.y * hi1 + dhv.y * xt1 + a1;
        const size_t ei = base + (size_t)t * 131072 + d;
        ((unsigned*)buf1b)[ei >> 1] = pk2bf(bv0, bv1);
        // fused space-LN -> bf16
        float u1 = bv0 + bv1, u2 = bv0 * bv0 + bv1 * bv1;
        #pragma unroll
        for (int o = 32; o > 0; o >>= 1) {
            u1 += __shfl_xor(u1, o);
            u2 += __shfl_xor(u2, o);
        }
        const float mu2 = u1 * (1.f / 128.f);
        const float rv2 = rsqrtf(u2 * (1.f / 128.f) - mu2 * mu2 + EPSV);
        ((unsigned*)xnb)[ei >> 1] = pk2bf((bv0 - mu2) * rv2 * sgv.x + sbv.x,
                                          (bv1 - mu2) * rv2 * sgv.y + sbv.y);
    }
    *(float4*)(hout + ((size_t)bhw * 128 + d) * 2) = make_float4(hr0, hi0, hr1, hi1);
}

// ----------------- Kernel W: pack weights (+ spec K/M precompute, merged)
__global__ __launch_bounds__(256) void k_pack(
    const float* __restrict__ cwr, const float* __restrict__ cwi,
    const float* __restrict__ cbr, const float* __restrict__ cbi,
    const float* __restrict__ w1r, const float* __restrict__ w1i,
    const float* __restrict__ b1r, const float* __restrict__ b1i,
    const float* __restrict__ w2r, const float* __restrict__ w2i,
    const float* __restrict__ b2r, const float* __restrict__ b2i,
    const float* __restrict__ ur, const float* __restrict__ ui,
    const float* __restrict__ vr, const float* __restrict__ vi,
    const float* __restrict__ dec, const float* __restrict__ omg,
    const float* __restrict__ dt,
    short* __restrict__ Bcv, short* __restrict__ W1p, short* __restrict__ W2p,
    float* __restrict__ biasc, float* __restrict__ bias1, float* __restrict__ bias2,
    float* __restrict__ Kb, float* __restrict__ Mb)
{
    const int idx = blockIdx.x * 256 + threadIdx.x;
    if (idx < 147456) {                       // conv frags
        const int f = idx >> 9, r = idx & 511;
        const int lane = r >> 3, j = r & 7;
        const int tap = f >> 5, kc = (f >> 3) & 3, nf = f & 7;
        const int n = nf * 16 + (lane & 15);
        const int k = kc * 32 + (lane >> 4) * 8 + j;
        const int co = n >> 1, po = n & 1, ci = k >> 1, pi = k & 1;
        const float wr = cwr[(co * 64 + ci) * 9 + tap];
        const float wi = cwi[(co * 64 + ci) * 9 + tap];
        const float val = po == 0 ? (pi == 0 ? wr : -wi) : (pi == 0 ? wi : wr);
        Bcv[idx] = f2bf(val);
    } else if (idx < 212992) {                // W1 frags
        const int i2 = idx - 147456;
        const int f = i2 >> 9, r = i2 & 511;
        const int lane = r >> 3, j = r & 7;
        const int kc = f >> 5, nf = f & 31;
        const int n = nf * 16 + (lane & 15);
        const int k = kc * 32 + (lane >> 4) * 8 + j;
        const int e = n >> 1, q = n & 1, c = k >> 1, p = k & 1;
        const float ar = w1r[c * 256 + e], ai = w1i[c * 256 + e];
        const float val = q == 0 ? (p == 0 ? ar : -ai) : (p == 0 ? ai : ar);
        W1p[i2] = f2bf(val);
    } else if (idx < 278528) {                // W2 frags
        const int i3 = idx - 212992;
        const int f = i3 >> 9, r = i3 & 511;
        const int lane = r >> 3, j = r & 7;
        const int kc = f >> 3, nf = f & 7;
        const int n = nf * 16 + (lane & 15);
        const int k = kc * 32 + (lane >> 4) * 8 + j;
        const int co = n >> 1, qo = n & 1, e = k >> 1, pe = k & 1;
        const float ar = w2r[e * 64 + co], ai = w2i[e * 64 + co];
        const float val = qo == 0 ? (pe == 0 ? ar : -ai) : (pe == 0 ? ai : ar);
        W2p[i3] = f2bf(val);
    } else if (idx < 279296) {                // biases
        const int i4 = idx - 278528;
        if (i4 < 128)      biasc[i4] = (i4 & 1) ? cbi[i4 >> 1] : cbr[i4 >> 1];
        else if (i4 < 640) { int n = i4 - 128; bias1[n] = (n & 1) ? b1i[n >> 1] : b1r[n >> 1]; }
        else if (i4 < 768) { int n = i4 - 640; bias2[n] = (n & 1) ? b2i[n >> 1] : b2r[n >> 1]; }
    } else if (idx < 281472) {                // Kb = U@V (2176 complex)
        const int id = idx - 279296;
        const int dd = id / 17, f = id % 17;
        float ar = 0.f, ai = 0.f;
        for (int r = 0; r < 32; ++r) {
            const float a = ur[dd * 32 + r], b = ui[dd * 32 + r];
            const float c = vr[r * 17 + f], e = vi[r * 17 + f];
            ar += a * c - b * e;
            ai += a * e + b * c;
        }
        Kb[id * 2] = ar; Kb[id * 2 + 1] = ai;
    } else if (idx < 282560) {                // Mb = exp(lam*dt) (1088 complex)
        const int m = idx - 281472;
        const int nn = m / 17, f = m % 17;
        const float xv = dec[f];
        const float sp = (xv > 20.f) ? xv : log1pf(expf(xv));
        const float dtv = dt[nn];
        const float mag = expf(-sp * dtv);
        float s, c; __sincosf(omg[f] * dtv, &s, &c);
        Mb[m * 2] = mag * c; Mb[m * 2 + 1] = mag * s;
    }
}

// -------------------- Kernel D: implicit-GEMM complex conv (round-11 exact:
// XCD swizzle + block-parity DFT stagger).
__global__ __launch_bounds__(256, 4) void k_conv(
    const unsigned short* __restrict__ xnb, const short* __restrict__ Bcv,
    const float* __restrict__ biasc, const float* __restrict__ Kb,
    const float* __restrict__ Mb, unsigned short* __restrict__ buf1b,
    const float* __restrict__ lnfg, const float* __restrict__ lnfb,
    unsigned short* __restrict__ xnb2)
{
    __shared__ char As[34816];   // bf16 halo -> 32KB f32 overlay later
    const int tid = threadIdx.x;
    const int lane = tid & 63, wn = tid >> 6;    // wave = N-split 0..3
    const int bid0 = blockIdx.x;
    const int swz = (bid0 & 7) * 128 + (bid0 >> 3);
    const int n = swz >> 4, hp = swz & 15;
    const int h0 = hp * 2;
    const int par = (swz ^ (swz >> 3) ^ (swz >> 6) ^ (swz >> 9)) & 1;

    for (int i = tid; i < 2176; i += 256) {
        const int p = i >> 4, seg = i & 15;
        const int hr = p / 34, wp = p - hr * 34;
        const int hh = h0 + hr - 1, ww = wp - 1;
        uint4 val = make_uint4(0u, 0u, 0u, 0u);
        if (hh >= 0 && hh < 32 && ww >= 0 && ww < 32)
            val = *(const uint4*)(xnb + ((size_t)((n * 32 + hh) * 32 + ww) * 128 + seg * 8));
        int byt = (p << 8) + (seg << 4);
        byt ^= (p & 7) << 4;
        *(uint4*)(As + byt) = val;
    }

    const int d = tid & 127;
    const int hb = tid >> 7;
    float zr[17], zi[17];
    auto do_dft = [&]() {
        const unsigned short* xrow = xnb + (size_t)((n * 32 + h0 + hb) * 32) * 128 + d;
        float xv[32];
        #pragma unroll
        for (int w = 0; w < 32; ++w) xv[w] = bf2f(xrow[(size_t)w * 128]);
        #pragma unroll
        for (int f = 0; f < 17; ++f) {
            zr[f] = xv[0] + ((f & 1) ? -xv[16] : xv[16]);
            zi[f] = 0.f;
        }
        #pragma unroll
        for (int w = 1; w <= 15; ++w) {
            const float E = xv[w] + xv[32 - w], O = xv[w] - xv[32 - w];
            #pragma unroll
            for (int f = 0; f < 17; ++f) {
                zr[f] = fmaf(E, COS32[(f * w) & 31], zr[f]);
                zi[f] = fmaf(-O, SIN32X[(f * w) & 31], zi[f]);
            }
        }
        #pragma unroll
        for (int f = 0; f < 17; ++f) {
            const float2 K = *(const float2*)(Kb + (d * 17 + f) * 2);
            const float2 M = *(const float2*)(Mb + (n * 17 + f) * 2);
            const float cr2 = (K.x * M.x - K.y * M.y) * (1.f / 32.f);
            const float ci2 = (K.x * M.y + K.y * M.x) * (1.f / 32.f);
            const float tr = zr[f] * cr2 - zi[f] * ci2;
            const float ti = zr[f] * ci2 + zi[f] * cr2;
            zr[f] = tr; zi[f] = ti;
        }
    };

    if (!par) do_dft();
    __syncthreads();

    int posb[4];
    #pragma unroll
    for (int fm = 0; fm < 4; ++fm) {
        const int m = fm * 16 + (lane & 15);
        posb[fm] = (m >> 5) * 34 + (m & 31);
    }
    const int kob = (lane >> 4) << 4;
    const char* bbase = (const char*)Bcv + (lane << 4);
    fx4 acc[4][2];
    #pragma unroll
    for (int a = 0; a < 4; ++a)
        #pragma unroll
        for (int b = 0; b < 2; ++b) acc[a][b] = (fx4){0.f, 0.f, 0.f, 0.f};

    for (int tap = 0; tap < 9; ++tap) {
        const int ty = (tap * 11) >> 5;
        const int tx = tap - ty * 3;
        const int shift = ty * 34 + tx;
        #pragma unroll
        for (int kc = 0; kc < 4; ++kc) {
            bfx8 af[4], bf_[2];
            #pragma unroll
            for (int fm = 0; fm < 4; ++fm) {
                const int pos = posb[fm] + shift;
                int byt = (pos << 8) + (kc << 6) + kob;
                byt ^= (pos & 7) << 4;
                af[fm] = *(const bfx8*)(As + byt);
            }
            #pragma unroll
            for (int fn = 0; fn < 2; ++fn)
                bf_[fn] = *(const bfx8*)(bbase + (((tap * 4 + kc) * 8 + wn * 2 + fn) << 10));
            #pragma unroll
            for (int fm = 0; fm < 4; ++fm)
                #pragma unroll
                for (int fn = 0; fn < 2; ++fn)
                    acc[fm][fn] = __builtin_amdgcn_mfma_f32_16x16x32_bf16(af[fm], bf_[fn], acc[fm][fn], 0, 0, 0);
        }
    }

    if (par) do_dft();
    __syncthreads();

    #pragma unroll
    for (int fn = 0; fn < 2; ++fn) {
        const int col = wn * 32 + fn * 16 + (lane & 15);
        const float bc = biasc[col];
        #pragma unroll
        for (int fm = 0; fm < 4; ++fm) {
            #pragma unroll
            for (int j = 0; j < 4; ++j) {
                const int r = fm * 16 + ((lane >> 4) << 2) + j;
                int byt = (r << 9) + (col << 2);
                byt ^= (r & 7) << 4;
                *(float*)(As + byt) = acc[fm][fn][j] + bc;
            }
        }
    }
    __syncthreads();

    {
        const int rb = hb * 32;
        {
            float s0 = zr[0] + zr[16];
            float sa = 0.f, sb = 0.f;
            #pragma unroll
            for (int f = 1; f <= 15; ++f) {
                sa += zr[f];
                sb += ((f & 1) ? -zr[f] : zr[f]);
            }
            int b0 = ((rb + 0) << 9) + (d << 2);   b0 ^= ((rb + 0) & 7) << 4;
            int b16 = ((rb + 16) << 9) + (d << 2); b16 ^= ((rb + 16) & 7) << 4;
            *(float*)(As + b0)  += s0 + 2.f * sa;
            *(float*)(As + b16) += s0 + 2.f * sb;
        }
        #pragma unroll
        for (int w = 1; w <= 15; ++w) {
            float A = 0.f, Bv = 0.f;
            #pragma unroll
            for (int f = 1; f <= 15; ++f) {
                A  = fmaf(zr[f], COS32[(f * w) & 31], A);
                Bv = fmaf(zi[f], SIN32X[(f * w) & 31], Bv);
            }
            const float base = zr[0] + ((w & 1) ? -zr[16] : zr[16]);
            int ba = ((rb + w) << 9) + (d << 2);        ba ^= ((rb + w) & 7) << 4;
            int bb = ((rb + 32 - w) << 9) + (d << 2);   bb ^= ((rb + 32 - w) & 7) << 4;
            *(float*)(As + ba) += base + 2.f * (A - Bv);
            *(float*)(As + bb) += base + 2.f * (A + Bv);
        }
    }
    __syncthreads();

    {
        const int p2 = tid >> 2, s2 = tid & 3;
        const int pb = n * 1024 + h0 * 32;
        unsigned short* bp = buf1b + (size_t)(pb + p2) * 128 + s2 * 32;
        uint4 rq[4];
        #pragma unroll
        for (int i = 0; i < 4; ++i) rq[i] = *(const uint4*)(bp + i * 8);
        float v[32];
        #pragma unroll
        for (int i = 0; i < 8; ++i) {
            int byt = (p2 << 9) + ((s2 * 32 + i * 4) << 2);
            byt ^= (p2 & 7) << 4;
            const float4 c = *(const float4*)(As + byt);
            const unsigned lo = ((const unsigned*)rq)[i * 2];
            const unsigned hi = ((const unsigned*)rq)[i * 2 + 1];
            v[4*i]   = c.x + bf2f((unsigned short)(lo & 0xffffu));
            v[4*i+1] = c.y + bf2f((unsigned short)(lo >> 16));
            v[4*i+2] = c.z + bf2f((unsigned short)(hi & 0xffffu));
            v[4*i+3] = c.w + bf2f((unsigned short)(hi >> 16));
        }
        float s1 = 0.f, sq = 0.f;
        #pragma unroll
        for (int i = 0; i < 32; ++i) { s1 += v[i]; sq += v[i] * v[i]; }
        s1 += __shfl_xor(s1, 1); sq += __shfl_xor(sq, 1);
        s1 += __shfl_xor(s1, 2); sq += __shfl_xor(sq, 2);
        const float mu = s1 * (1.f / 128.f);
        const float rv = rsqrtf(sq * (1.f / 128.f) - mu * mu + EPSV);
        #pragma unroll
        for (int i = 0; i < 4; ++i) {
            uint4 o;
            o.x = pk2bf(v[8*i],   v[8*i+1]); o.y = pk2bf(v[8*i+2], v[8*i+3]);
            o.z = pk2bf(v[8*i+4], v[8*i+5]); o.w = pk2bf(v[8*i+6], v[8*i+7]);
            *(uint4*)(bp + i * 8) = o;
        }
        const float4* g4 = (const float4*)(lnfg + s2 * 32);
        const float4* b4 = (const float4*)(lnfb + s2 * 32);
        unsigned pk[16];
        #pragma unroll
        for (int i = 0; i < 8; ++i) {
            const float4 g = g4[i], bb = b4[i];
            pk[2*i]   = pk2bf((v[4*i]   - mu) * rv * g.x + bb.x,
                              (v[4*i+1] - mu) * rv * g.y + bb.y);
            pk[2*i+1] = pk2bf((v[4*i+2] - mu) * rv * g.z + bb.z,
                              (v[4*i+3] - mu) * rv * g.w + bb.w);
        }
        unsigned short* op = xnb2 + (size_t)(pb + p2) * 128 + s2 * 32;
        *(uint4*)(op)      = make_uint4(pk[0], pk[1], pk[2], pk[3]);
        *(uint4*)(op + 8)  = make_uint4(pk[4], pk[5], pk[6], pk[7]);
        *(uint4*)(op + 16) = make_uint4(pk[8], pk[9], pk[10], pk[11]);
        *(uint4*)(op + 24) = make_uint4(pk[12], pk[13], pk[14], pk[15]);
    }
}

// ---------------- Kernel G: complex MLP via MFMA, M=64/block processed in
// TWO 32-pos halves. Hs shrinks 64KB -> 32KB (4 blocks/CU) and accumulators
// halve (a1[2][4], a2[2]) — target VGPR <= 64 for 8 waves/SIMD. No min-waves
// bound: if allocator lands >64, failure mode is neutral occupancy, NOT spill.
__global__ __launch_bounds__(512) void k_mlp(
    const unsigned short* __restrict__ xnb, const unsigned short* __restrict__ resb,
    const short* __restrict__ W1p, const short* __restrict__ W2p,
    const float* __restrict__ bias1, const float* __restrict__ bias2,
    float* __restrict__ outp)
{
    __shared__ char Hs[32768];   // 32 pos x 1024B bf16; overlay 16KB f32
    const int tid = threadIdx.x;
    const int lane = tid & 63, wid = tid >> 6;   // wid 0..7 = e-split
    const size_t m0 = (size_t)blockIdx.x * 64;
    const int kob = (lane >> 4) << 4;

    for (int hM = 0; hM < 2; ++hM) {
        const size_t pb = m0 + hM * 32;
        // ---- GEMM1: 32 pos x 512 e, K=128. wave handles e-frags wid*4..+3.
        fx4 a1[2][4];
        #pragma unroll
        for (int a = 0; a < 2; ++a)
            #pragma unroll
            for (int b = 0; b < 4; ++b) a1[a][b] = (fx4){0.f, 0.f, 0.f, 0.f};
        const unsigned short* abase = xnb + pb * 128;
        #pragma unroll
        for (int kc = 0; kc < 4; ++kc) {
            bfx8 xa[2];
            #pragma unroll
            for (int pj = 0; pj < 2; ++pj)
                xa[pj] = *(const bfx8*)(abase + (pj * 16 + (lane & 15)) * 128 + kc * 32 + (lane >> 4) * 8);
            #pragma unroll
            for (int eo = 0; eo < 2; ++eo) {
                bfx8 wb[2];
                #pragma unroll
                for (int k2 = 0; k2 < 2; ++k2)
                    wb[k2] = *(const bfx8*)((const char*)W1p + ((kc * 32 + wid * 4 + eo * 2 + k2) << 10) + (lane << 4));
                #pragma unroll
                for (int pj = 0; pj < 2; ++pj)
                    #pragma unroll
                    for (int k2 = 0; k2 < 2; ++k2)
                        a1[pj][eo * 2 + k2] = __builtin_amdgcn_mfma_f32_16x16x32_bf16(xa[pj], wb[k2], a1[pj][eo * 2 + k2], 0, 0, 0);
            }
        }
        __syncthreads();   // prior half's overlay reads done; Hs reusable
        // ---- bias + gelu -> Hs (bf16), 32 scalar b16 writes/lane
        #pragma unroll
        for (int ef = 0; ef < 4; ++ef) {
            const int c = (wid * 4 + ef) * 16 + (lane & 15);
            const float bv = bias1[c];
            #pragma unroll
            for (int pj = 0; pj < 2; ++pj) {
                #pragma unroll
                for (int j = 0; j < 4; ++j) {
                    const int r = pj * 16 + ((lane >> 4) << 2) + j;   // 0..31
                    const float g = geluf(a1[pj][ef][j] + bv);
                    int byt = (r << 10) + (c << 1);
                    byt ^= (r & 7) << 4;
                    *(short*)(Hs + byt) = f2bf(g);
                }
            }
        }
        __syncthreads();
        // ---- GEMM2: 32 pos x 128 out, K=1024 bytes (512 e)
        fx4 a2[2];
        a2[0] = (fx4){0.f, 0.f, 0.f, 0.f};
        a2[1] = (fx4){0.f, 0.f, 0.f, 0.f};
        #pragma unroll
        for (int kc = 0; kc < 16; ++kc) {
            bfx8 ha[2], wb;
            #pragma unroll
            for (int fm = 0; fm < 2; ++fm) {
                const int r = fm * 16 + (lane & 15);
                int byt = (r << 10) + (kc << 6) + kob;
                byt ^= (r & 7) << 4;
                ha[fm] = *(const bfx8*)(Hs + byt);
            }
            wb = *(const bfx8*)((const char*)W2p + ((kc * 8 + wid) << 10) + (lane << 4));
            #pragma unroll
            for (int fm = 0; fm < 2; ++fm)
                a2[fm] = __builtin_amdgcn_mfma_f32_16x16x32_bf16(ha[fm], wb, a2[fm], 0, 0, 0);
        }
        __syncthreads();   // Hs reads done -> f32 overlay (32 x 512B = 16KB)
        {
            const int col = wid * 16 + (lane & 15);
            const float bv = bias2[col];
            #pragma unroll
            for (int fm = 0; fm < 2; ++fm) {
                #pragma unroll
                for (int j = 0; j < 4; ++j) {
                    const int r = fm * 16 + ((lane >> 4) << 2) + j;   // 0..31
                    int byt = (r << 9) + (col << 2);
                    byt ^= (r & 7) << 4;
                    *(float*)(Hs + byt) = a2[fm][j] + bv;
                }
            }
        }
        __syncthreads();
        // ---- coalesced out: 32 pos x 512B = 16KB, 512 thr x 16B x 2 iters
        #pragma unroll
        for (int i = 0; i < 2; ++i) {
            const int bo = i * 8192 + tid * 16;
            const int r = bo >> 9;
            const int cb = bo & 511;
            int byt = bo ^ ((r & 7) << 4);
            float4 v = *(const float4*)(Hs + byt);
            const size_t o = (pb + r) * 128 + (cb >> 2);
            const unsigned* rp = (const unsigned*)(resb + o);
            const unsigned r0 = rp[0], r1 = rp[1];
            v.x += bf2f((unsigned short)(r0 & 0xffffu));
            v.y += bf2f((unsigned short)(r0 >> 16));
            v.z += bf2f((unsigned short)(r1 & 0xffffu));
            v.w += bf2f((unsigned short)(r1 >> 16));
            *(float4*)(outp + o) = v;
        }
    }
}

extern "C" void kernel_launch(void* const* d_in, const int* in_sizes, int n_in,
                              void* d_out, int out_size, void* d_ws, size_t ws_size,
                              hipStream_t stream) {
    const float* x          = (const float*)d_in[0];
    const float* dt         = (const float*)d_in[1];
    const float* ln_time_g  = (const float*)d_in[2];
    const float* ln_time_b  = (const float*)d_in[3];
    const float* ln_space_g = (const float*)d_in[4];
    const float* ln_space_b = (const float*)d_in[5];
    const float* ln_feat_g  = (const float*)d_in[6];
    const float* ln_feat_b  = (const float*)d_in[7];
    const float* ham_omega  = (const float*)d_in[8];
    const float* ham_bin    = (const float*)d_in[9];
    const float* ham_cr     = (const float*)d_in[10];
    const float* ham_ci     = (const float*)d_in[11];
    const float* ham_d      = (const float*)d_in[12];
    const float* cliff_wr   = (const float*)d_in[13];
    const float* cliff_wi   = (const float*)d_in[14];
    const float* cliff_br   = (const float*)d_in[15];
    const float* cliff_bi   = (const float*)d_in[16];
    const float* spec_ur    = (const float*)d_in[17];
    const float* spec_ui    = (const float*)d_in[18];
    const float* spec_vr    = (const float*)d_in[19];
    const float* spec_vi    = (const float*)d_in[20];
    const float* spec_decay = (const float*)d_in[21];
    const float* spec_omega = (const float*)d_in[22];
    const float* w1r        = (const float*)d_in[23];
    const float* w1i        = (const float*)d_in[24];
    const float* b1r        = (const float*)d_in[25];
    const float* b1i        = (const float*)d_in[26];
    const float* w2r        = (const float*)d_in[27];
    const float* w2i        = (const float*)d_in[28];
    const float* b2r        = (const float*)d_in[29];
    const float* b2i        = (const float*)d_in[30];

    float* out = (float*)d_out;
    const size_t NX = 8388608;               // B*T*H*W*C*2
    float* hout = out + NX;

    float* ws = (float*)d_ws;
    unsigned short* buf1b = (unsigned short*)ws;                 // 8388608 bf16
    unsigned short* xnb   = (unsigned short*)(ws + 4194304);     // 8388608 bf16
    unsigned short* xnb2  = (unsigned short*)(ws + 8388608);     // 8388608 bf16
    short* Bcv  = (short*)(ws + 12582912);                       // 147456 bf16
    short* W1p  = (short*)(ws + 12656640);                       // 65536 bf16
    short* W2p  = (short*)(ws + 12689408);                       // 65536 bf16
    float* biasc = ws + 12722176;                                // 128
    float* bias1 = ws + 12722304;                                // 512
    float* bias2 = ws + 12722816;                                // 128
    float* Kb    = ws + 12722944;                                // 4352
    float* Mb    = ws + 12727296;                                // 2176

    k_pack<<<1104, 256, 0, stream>>>(cliff_wr, cliff_wi, cliff_br, cliff_bi,
                                     w1r, w1i, b1r, b1i, w2r, w2i, b2r, b2i,
                                     spec_ur, spec_ui, spec_vr, spec_vi,
                                     spec_decay, spec_omega, dt,
                                     Bcv, W1p, W2p, biasc, bias1, bias2, Kb, Mb);
    k_time_scan<<<1024, 256, 0, stream>>>(x, dt, ln_time_g, ln_time_b,
                                          ham_omega, ham_bin, ham_cr, ham_ci,
                                          ham_d, ln_space_g, ln_space_b,
                                          buf1b, xnb, hout);
    k_conv<<<1024, 256, 0, stream>>>(xnb, Bcv, biasc, Kb, Mb, buf1b,
                                     ln_feat_g, ln_feat_b, xnb2);
    k_mlp<<<1024, 512, 0, stream>>>(xnb2, buf1b, W1p, W2p, bias1, bias2, out);
}

// Round 14
// 109.910 us; speedup vs baseline: 1.2274x; 1.2274x over previous
//
#include <hip/hip_runtime.h>
#include <math.h>

#define EPSV 1e-5f

typedef short bfx8 __attribute__((ext_vector_type(8)));
typedef float fx4  __attribute__((ext_vector_type(4)));

// cos/sin(2*pi*j/32)
constexpr float COS32[32] = {
     1.00000000f,  0.98078528f,  0.92387953f,  0.83146961f,
     0.70710678f,  0.55557023f,  0.38268343f,  0.19509032f,
     0.00000000f, -0.19509032f, -0.38268343f, -0.55557023f,
    -0.70710678f, -0.83146961f, -0.92387953f, -0.98078528f,
    -1.00000000f, -0.98078528f, -0.92387953f, -0.83146961f,
    -0.70710678f, -0.55557023f, -0.38268343f, -0.19509032f,
     0.00000000f,  0.19509032f,  0.38268343f,  0.55557023f,
     0.70710678f,  0.83146961f,  0.92387953f,  0.98078528f };
constexpr float SIN32X[32] = {
     0.00000000f,  0.19509032f,  0.38268343f,  0.55557023f,
     0.70710678f,  0.83146961f,  0.92387953f,  0.98078528f,
     1.00000000f,  0.98078528f,  0.92387953f,  0.83146961f,
     0.70710678f,  0.55557023f,  0.38268343f,  0.19509032f,
     0.00000000f, -0.19509032f, -0.38268343f, -0.55557023f,
    -0.70710678f, -0.83146961f, -0.92387953f, -0.98078528f,
    -1.00000000f, -0.98078528f, -0.92387953f, -0.83146961f,
    -0.70710678f, -0.55557023f, -0.38268343f, -0.19509032f };

__device__ __forceinline__ short f2bf(float f) {
    unsigned u = __float_as_uint(f);
    u += 0x7fffu + ((u >> 16) & 1u);
    return (short)(u >> 16);
}
__device__ __forceinline__ unsigned pk2bf(float a, float b) {
    return (unsigned)(unsigned short)f2bf(a) | ((unsigned)(unsigned short)f2bf(b) << 16);
}
__device__ __forceinline__ float bf2f(unsigned short h) {
    return __uint_as_float(((unsigned)h) << 16);
}
__device__ __forceinline__ float geluf(float x) {
    float x2 = x * x;
    float u2 = x * fmaf(0.0713548162726f, x2, 1.59576912161f);
    float e  = __expf(-u2);
    return x * __builtin_amdgcn_rcpf(1.f + e);
}

// ---------------- Fused Kernel A+W: blocks 0..1023 = time-LN+scan+space-LN,
// blocks 1024..2127 = weight pack + spec K/M precompute. Independent work
// merged into one launch so pack hides under the latency-bound scan waves.
__global__ __launch_bounds__(256) void k_ts_pack(
    const float* __restrict__ x, const float* __restrict__ dt,
    const float* __restrict__ lng, const float* __restrict__ lnb,
    const float* __restrict__ om, const float* __restrict__ bin,
    const float* __restrict__ hcr, const float* __restrict__ hci,
    const float* __restrict__ hd,
    const float* __restrict__ lnsg, const float* __restrict__ lnsb,
    unsigned short* __restrict__ buf1b, unsigned short* __restrict__ xnb,
    float* __restrict__ hout,
    // pack inputs/outputs:
    const float* __restrict__ cwr, const float* __restrict__ cwi,
    const float* __restrict__ cbr, const float* __restrict__ cbi,
    const float* __restrict__ w1r, const float* __restrict__ w1i,
    const float* __restrict__ b1r, const float* __restrict__ b1i,
    const float* __restrict__ w2r, const float* __restrict__ w2i,
    const float* __restrict__ b2r, const float* __restrict__ b2i,
    const float* __restrict__ ur, const float* __restrict__ ui,
    const float* __restrict__ vr, const float* __restrict__ vi,
    const float* __restrict__ dec, const float* __restrict__ omg,
    short* __restrict__ Bcv, short* __restrict__ W1p, short* __restrict__ W2p,
    float* __restrict__ biasc, float* __restrict__ bias1, float* __restrict__ bias2,
    float* __restrict__ Kb, float* __restrict__ Mb)
{
    if (blockIdx.x >= 1024) {
        // ----------------------------- pack branch
        const int idx = (blockIdx.x - 1024) * 256 + threadIdx.x;
        if (idx < 147456) {                       // conv frags
            const int f = idx >> 9, r = idx & 511;
            const int lane = r >> 3, j = r & 7;
            const int tap = f >> 5, kc = (f >> 3) & 3, nf = f & 7;
            const int n = nf * 16 + (lane & 15);
            const int k = kc * 32 + (lane >> 4) * 8 + j;
            const int co = n >> 1, po = n & 1, ci = k >> 1, pi = k & 1;
            const float wr = cwr[(co * 64 + ci) * 9 + tap];
            const float wi = cwi[(co * 64 + ci) * 9 + tap];
            const float val = po == 0 ? (pi == 0 ? wr : -wi) : (pi == 0 ? wi : wr);
            Bcv[idx] = f2bf(val);
        } else if (idx < 212992) {                // W1 frags
            const int i2 = idx - 147456;
            const int f = i2 >> 9, r = i2 & 511;
            const int lane = r >> 3, j = r & 7;
            const int kc = f >> 5, nf = f & 31;
            const int n = nf * 16 + (lane & 15);
            const int k = kc * 32 + (lane >> 4) * 8 + j;
            const int e = n >> 1, q = n & 1, c = k >> 1, p = k & 1;
            const float ar = w1r[c * 256 + e], ai = w1i[c * 256 + e];
            const float val = q == 0 ? (p == 0 ? ar : -ai) : (p == 0 ? ai : ar);
            W1p[i2] = f2bf(val);
        } else if (idx < 278528) {                // W2 frags
            const int i3 = idx - 212992;
            const int f = i3 >> 9, r = i3 & 511;
            const int lane = r >> 3, j = r & 7;
            const int kc = f >> 3, nf = f & 7;
            const int n = nf * 16 + (lane & 15);
            const int k = kc * 32 + (lane >> 4) * 8 + j;
            const int co = n >> 1, qo = n & 1, e = k >> 1, pe = k & 1;
            const float ar = w2r[e * 64 + co], ai = w2i[e * 64 + co];
            const float val = qo == 0 ? (pe == 0 ? ar : -ai) : (pe == 0 ? ai : ar);
            W2p[i3] = f2bf(val);
        } else if (idx < 279296) {                // biases
            const int i4 = idx - 278528;
            if (i4 < 128)      biasc[i4] = (i4 & 1) ? cbi[i4 >> 1] : cbr[i4 >> 1];
            else if (i4 < 640) { int n = i4 - 128; bias1[n] = (n & 1) ? b1i[n >> 1] : b1r[n >> 1]; }
            else if (i4 < 768) { int n = i4 - 640; bias2[n] = (n & 1) ? b2i[n >> 1] : b2r[n >> 1]; }
        } else if (idx < 281472) {                // Kb = U@V (2176 complex)
            const int id = idx - 279296;
            const int dd = id / 17, f = id % 17;
            float ar = 0.f, ai = 0.f;
            for (int r = 0; r < 32; ++r) {
                const float a = ur[dd * 32 + r], b = ui[dd * 32 + r];
                const float c = vr[r * 17 + f], e = vi[r * 17 + f];
                ar += a * c - b * e;
                ai += a * e + b * c;
            }
            Kb[id * 2] = ar; Kb[id * 2 + 1] = ai;
        } else if (idx < 282560) {                // Mb = exp(lam*dt) (1088 complex)
            const int m = idx - 281472;
            const int nn = m / 17, f = m % 17;
            const float xv = dec[f];
            const float sp = (xv > 20.f) ? xv : log1pf(expf(xv));
            const float dtv = dt[nn];
            const float mag = expf(-sp * dtv);
            float s, c; __sincosf(omg[f] * dtv, &s, &c);
            Mb[m * 2] = mag * c; Mb[m * 2 + 1] = mag * s;
        }
        return;
    }
    // ----------------------------- time-scan branch (round-11 exact)
    const int wv = threadIdx.x >> 6, lane = threadIdx.x & 63;
    const int bhw = blockIdx.x * 4 + wv;
    const int b = bhw >> 10, hw = bhw & 1023;
    const int d = lane << 1;
    const float2 gd = *(const float2*)(lng + d);
    const float2 bd = *(const float2*)(lnb + d);
    const float2 omv = *(const float2*)(om + d);
    const float2 biv = *(const float2*)(bin + d);
    const float2 crv = *(const float2*)(hcr + d);
    const float2 civ = *(const float2*)(hci + d);
    const float2 dhv = *(const float2*)(hd + d);
    const float2 sgv = *(const float2*)(lnsg + d);
    const float2 sbv = *(const float2*)(lnsb + d);
    const size_t base = (size_t)b * 2097152 + (size_t)hw * 128;
    float2 xv[16]; float dts[16];
    #pragma unroll
    for (int t = 0; t < 16; ++t) {
        xv[t] = *(const float2*)(x + base + (size_t)t * 131072 + d);
        dts[t] = dt[b * 16 + t];
    }
    float hr0 = 0.f, hi0 = 0.f, hr1 = 0.f, hi1 = 0.f;
    #pragma unroll
    for (int t = 0; t < 16; ++t) {
        const float a0 = xv[t].x, a1 = xv[t].y;
        float s1 = a0 + a1;
        float s2 = a0 * a0 + a1 * a1;
        #pragma unroll
        for (int o = 32; o > 0; o >>= 1) {
            s1 += __shfl_xor(s1, o);
            s2 += __shfl_xor(s2, o);
        }
        const float mu = s1 * (1.f / 128.f);
        const float rv = rsqrtf(s2 * (1.f / 128.f) - mu * mu + EPSV);
        const float xt0 = (a0 - mu) * rv * gd.x + bd.x;
        const float xt1 = (a1 - mu) * rv * gd.y + bd.y;
        float sp0, cp0, sp1, cp1;
        __sincosf(omv.x * dts[t], &sp0, &cp0);
        __sincosf(omv.y * dts[t], &sp1, &cp1);
        float nhr = cp0 * hr0 - sp0 * hi0 + biv.x * xt0;
        float nhi = cp0 * hi0 + sp0 * hr0;
        hr0 = nhr; hi0 = nhi;
        nhr = cp1 * hr1 - sp1 * hi1 + biv.y * xt1;
        nhi = cp1 * hi1 + sp1 * hr1;
        hr1 = nhr; hi1 = nhi;
        const float bv0 = crv.x * hr0 - civ.x * hi0 + dhv.x * xt0 + a0;
        const float bv1 = crv.y * hr1 - civ.y * hi1 + dhv.y * xt1 + a1;
        const size_t ei = base + (size_t)t * 131072 + d;
        ((unsigned*)buf1b)[ei >> 1] = pk2bf(bv0, bv1);
        // fused space-LN -> bf16
        float u1 = bv0 + bv1, u2 = bv0 * bv0 + bv1 * bv1;
        #pragma unroll
        for (int o = 32; o > 0; o >>= 1) {
            u1 += __shfl_xor(u1, o);
            u2 += __shfl_xor(u2, o);
        }
        const float mu2 = u1 * (1.f / 128.f);
        const float rv2 = rsqrtf(u2 * (1.f / 128.f) - mu2 * mu2 + EPSV);
        ((unsigned*)xnb)[ei >> 1] = pk2bf((bv0 - mu2) * rv2 * sgv.x + sbv.x,
                                          (bv1 - mu2) * rv2 * sgv.y + sbv.y);
    }
    *(float4*)(hout + ((size_t)bhw * 128 + d) * 2) = make_float4(hr0, hi0, hr1, hi1);
}

// -------------------- Kernel D: implicit-GEMM complex conv (round-11 exact:
// XCD swizzle + block-parity DFT stagger).
__global__ __launch_bounds__(256, 4) void k_conv(
    const unsigned short* __restrict__ xnb, const short* __restrict__ Bcv,
    const float* __restrict__ biasc, const float* __restrict__ Kb,
    const float* __restrict__ Mb, unsigned short* __restrict__ buf1b,
    const float* __restrict__ lnfg, const float* __restrict__ lnfb,
    unsigned short* __restrict__ xnb2)
{
    __shared__ char As[34816];   // bf16 halo -> 32KB f32 overlay later
    const int tid = threadIdx.x;
    const int lane = tid & 63, wn = tid >> 6;    // wave = N-split 0..3
    const int bid0 = blockIdx.x;
    const int swz = (bid0 & 7) * 128 + (bid0 >> 3);
    const int n = swz >> 4, hp = swz & 15;
    const int h0 = hp * 2;
    const int par = (swz ^ (swz >> 3) ^ (swz >> 6) ^ (swz >> 9)) & 1;

    for (int i = tid; i < 2176; i += 256) {
        const int p = i >> 4, seg = i & 15;
        const int hr = p / 34, wp = p - hr * 34;
        const int hh = h0 + hr - 1, ww = wp - 1;
        uint4 val = make_uint4(0u, 0u, 0u, 0u);
        if (hh >= 0 && hh < 32 && ww >= 0 && ww < 32)
            val = *(const uint4*)(xnb + ((size_t)((n * 32 + hh) * 32 + ww) * 128 + seg * 8));
        int byt = (p << 8) + (seg << 4);
        byt ^= (p & 7) << 4;
        *(uint4*)(As + byt) = val;
    }

    const int d = tid & 127;
    const int hb = tid >> 7;
    float zr[17], zi[17];
    auto do_dft = [&]() {
        const unsigned short* xrow = xnb + (size_t)((n * 32 + h0 + hb) * 32) * 128 + d;
        float xv[32];
        #pragma unroll
        for (int w = 0; w < 32; ++w) xv[w] = bf2f(xrow[(size_t)w * 128]);
        #pragma unroll
        for (int f = 0; f < 17; ++f) {
            zr[f] = xv[0] + ((f & 1) ? -xv[16] : xv[16]);
            zi[f] = 0.f;
        }
        #pragma unroll
        for (int w = 1; w <= 15; ++w) {
            const float E = xv[w] + xv[32 - w], O = xv[w] - xv[32 - w];
            #pragma unroll
            for (int f = 0; f < 17; ++f) {
                zr[f] = fmaf(E, COS32[(f * w) & 31], zr[f]);
                zi[f] = fmaf(-O, SIN32X[(f * w) & 31], zi[f]);
            }
        }
        #pragma unroll
        for (int f = 0; f < 17; ++f) {
            const float2 K = *(const float2*)(Kb + (d * 17 + f) * 2);
            const float2 M = *(const float2*)(Mb + (n * 17 + f) * 2);
            const float cr2 = (K.x * M.x - K.y * M.y) * (1.f / 32.f);
            const float ci2 = (K.x * M.y + K.y * M.x) * (1.f / 32.f);
            const float tr = zr[f] * cr2 - zi[f] * ci2;
            const float ti = zr[f] * ci2 + zi[f] * cr2;
            zr[f] = tr; zi[f] = ti;
        }
    };

    if (!par) do_dft();
    __syncthreads();

    int posb[4];
    #pragma unroll
    for (int fm = 0; fm < 4; ++fm) {
        const int m = fm * 16 + (lane & 15);
        posb[fm] = (m >> 5) * 34 + (m & 31);
    }
    const int kob = (lane >> 4) << 4;
    const char* bbase = (const char*)Bcv + (lane << 4);
    fx4 acc[4][2];
    #pragma unroll
    for (int a = 0; a < 4; ++a)
        #pragma unroll
        for (int b = 0; b < 2; ++b) acc[a][b] = (fx4){0.f, 0.f, 0.f, 0.f};

    for (int tap = 0; tap < 9; ++tap) {
        const int ty = (tap * 11) >> 5;
        const int tx = tap - ty * 3;
        const int shift = ty * 34 + tx;
        #pragma unroll
        for (int kc = 0; kc < 4; ++kc) {
            bfx8 af[4], bf_[2];
            #pragma unroll
            for (int fm = 0; fm < 4; ++fm) {
                const int pos = posb[fm] + shift;
                int byt = (pos << 8) + (kc << 6) + kob;
                byt ^= (pos & 7) << 4;
                af[fm] = *(const bfx8*)(As + byt);
            }
            #pragma unroll
            for (int fn = 0; fn < 2; ++fn)
                bf_[fn] = *(const bfx8*)(bbase + (((tap * 4 + kc) * 8 + wn * 2 + fn) << 10));
            #pragma unroll
            for (int fm = 0; fm < 4; ++fm)
                #pragma unroll
                for (int fn = 0; fn < 2; ++fn)
                    acc[fm][fn] = __builtin_amdgcn_mfma_f32_16x16x32_bf16(af[fm], bf_[fn], acc[fm][fn], 0, 0, 0);
        }
    }

    if (par) do_dft();
    __syncthreads();

    #pragma unroll
    for (int fn = 0; fn < 2; ++fn) {
        const int col = wn * 32 + fn * 16 + (lane & 15);
        const float bc = biasc[col];
        #pragma unroll
        for (int fm = 0; fm < 4; ++fm) {
            #pragma unroll
            for (int j = 0; j < 4; ++j) {
                const int r = fm * 16 + ((lane >> 4) << 2) + j;
                int byt = (r << 9) + (col << 2);
                byt ^= (r & 7) << 4;
                *(float*)(As + byt) = acc[fm][fn][j] + bc;
            }
        }
    }
    __syncthreads();

    {
        const int rb = hb * 32;
        {
            float s0 = zr[0] + zr[16];
            float sa = 0.f, sb = 0.f;
            #pragma unroll
            for (int f = 1; f <= 15; ++f) {
                sa += zr[f];
                sb += ((f & 1) ? -zr[f] : zr[f]);
            }
            int b0 = ((rb + 0) << 9) + (d << 2);   b0 ^= ((rb + 0) & 7) << 4;
            int b16 = ((rb + 16) << 9) + (d << 2); b16 ^= ((rb + 16) & 7) << 4;
            *(float*)(As + b0)  += s0 + 2.f * sa;
            *(float*)(As + b16) += s0 + 2.f * sb;
        }
        #pragma unroll
        for (int w = 1; w <= 15; ++w) {
            float A = 0.f, Bv = 0.f;
            #pragma unroll
            for (int f = 1; f <= 15; ++f) {
                A  = fmaf(zr[f], COS32[(f * w) & 31], A);
                Bv = fmaf(zi[f], SIN32X[(f * w) & 31], Bv);
            }
            const float base = zr[0] + ((w & 1) ? -zr[16] : zr[16]);
            int ba = ((rb + w) << 9) + (d << 2);        ba ^= ((rb + w) & 7) << 4;
            int bb = ((rb + 32 - w) << 9) + (d << 2);   bb ^= ((rb + 32 - w) & 7) << 4;
            *(float*)(As + ba) += base + 2.f * (A - Bv);
            *(float*)(As + bb) += base + 2.f * (A + Bv);
        }
    }
    __syncthreads();

    {
        const int p2 = tid >> 2, s2 = tid & 3;
        const int pb = n * 1024 + h0 * 32;
        unsigned short* bp = buf1b + (size_t)(pb + p2) * 128 + s2 * 32;
        uint4 rq[4];
        #pragma unroll
        for (int i = 0; i < 4; ++i) rq[i] = *(const uint4*)(bp + i * 8);
        float v[32];
        #pragma unroll
        for (int i = 0; i < 8; ++i) {
            int byt = (p2 << 9) + ((s2 * 32 + i * 4) << 2);
            byt ^= (p2 & 7) << 4;
            const float4 c = *(const float4*)(As + byt);
            const unsigned lo = ((const unsigned*)rq)[i * 2];
            const unsigned hi = ((const unsigned*)rq)[i * 2 + 1];
            v[4*i]   = c.x + bf2f((unsigned short)(lo & 0xffffu));
            v[4*i+1] = c.y + bf2f((unsigned short)(lo >> 16));
            v[4*i+2] = c.z + bf2f((unsigned short)(hi & 0xffffu));
            v[4*i+3] = c.w + bf2f((unsigned short)(hi >> 16));
        }
        float s1 = 0.f, sq = 0.f;
        #pragma unroll
        for (int i = 0; i < 32; ++i) { s1 += v[i]; sq += v[i] * v[i]; }
        s1 += __shfl_xor(s1, 1); sq += __shfl_xor(sq, 1);
        s1 += __shfl_xor(s1, 2); sq += __shfl_xor(sq, 2);
        const float mu = s1 * (1.f / 128.f);
        const float rv = rsqrtf(sq * (1.f / 128.f) - mu * mu + EPSV);
        #pragma unroll
        for (int i = 0; i < 4; ++i) {
            uint4 o;
            o.x = pk2bf(v[8*i],   v[8*i+1]); o.y = pk2bf(v[8*i+2], v[8*i+3]);
            o.z = pk2bf(v[8*i+4], v[8*i+5]); o.w = pk2bf(v[8*i+6], v[8*i+7]);
            *(uint4*)(bp + i * 8) = o;
        }
        const float4* g4 = (const float4*)(lnfg + s2 * 32);
        const float4* b4 = (const float4*)(lnfb + s2 * 32);
        unsigned pk[16];
        #pragma unroll
        for (int i = 0; i < 8; ++i) {
            const float4 g = g4[i], bb = b4[i];
            pk[2*i]   = pk2bf((v[4*i]   - mu) * rv * g.x + bb.x,
                              (v[4*i+1] - mu) * rv * g.y + bb.y);
            pk[2*i+1] = pk2bf((v[4*i+2] - mu) * rv * g.z + bb.z,
                              (v[4*i+3] - mu) * rv * g.w + bb.w);
        }
        unsigned short* op = xnb2 + (size_t)(pb + p2) * 128 + s2 * 32;
        *(uint4*)(op)      = make_uint4(pk[0], pk[1], pk[2], pk[3]);
        *(uint4*)(op + 8)  = make_uint4(pk[4], pk[5], pk[6], pk[7]);
        *(uint4*)(op + 16) = make_uint4(pk[8], pk[9], pk[10], pk[11]);
        *(uint4*)(op + 24) = make_uint4(pk[12], pk[13], pk[14], pk[15]);
    }
}

// ---------------- Kernel G: complex MLP via MFMA, M=64/block (round-11 exact)
__global__ __launch_bounds__(512, 4) void k_mlp(
    const unsigned short* __restrict__ xnb, const unsigned short* __restrict__ resb,
    const short* __restrict__ W1p, const short* __restrict__ W2p,
    const float* __restrict__ bias1, const float* __restrict__ bias2,
    float* __restrict__ outp)
{
    __shared__ char Hs[65536];   // 64 x 1024B bf16 -> later 32KB f32 overlay
    const int tid = threadIdx.x;
    const int lane = tid & 63, wid = tid >> 6;   // wid 0..7
    const size_t m0 = (size_t)blockIdx.x * 64;
    const int kob = (lane >> 4) << 4;

    fx4 a1[4][4];
    #pragma unroll
    for (int a = 0; a < 4; ++a)
        #pragma unroll
        for (int b = 0; b < 4; ++b) a1[a][b] = (fx4){0.f, 0.f, 0.f, 0.f};
    const unsigned short* abase = xnb + m0 * 128;
    #pragma unroll
    for (int kc = 0; kc < 4; ++kc) {
        bfx8 xa[4], wb[4];
        #pragma unroll
        for (int fm = 0; fm < 4; ++fm)
            xa[fm] = *(const bfx8*)(abase + (fm * 16 + (lane & 15)) * 128 + kc * 32 + (lane >> 4) * 8);
        #pragma unroll
        for (int fn = 0; fn < 4; ++fn)
            wb[fn] = *(const bfx8*)((const char*)W1p + ((kc * 32 + wid * 4 + fn) << 10) + (lane << 4));
        #pragma unroll
        for (int fm = 0; fm < 4; ++fm)
            #pragma unroll
            for (int fn = 0; fn < 4; ++fn)
                a1[fm][fn] = __builtin_amdgcn_mfma_f32_16x16x32_bf16(xa[fm], wb[fn], a1[fm][fn], 0, 0, 0);
    }
    #pragma unroll
    for (int fn = 0; fn < 4; ++fn) {
        const int c = (wid * 4 + fn) * 16 + (lane & 15);
        const float bv = bias1[c];
        #pragma unroll
        for (int fm = 0; fm < 4; ++fm) {
            #pragma unroll
            for (int j = 0; j < 4; ++j) {
                const int r = fm * 16 + ((lane >> 4) << 2) + j;
                const float g = geluf(a1[fm][fn][j] + bv);
                int byt = (r << 10) + (c << 1);
                byt ^= (r & 7) << 4;
                *(short*)(Hs + byt) = f2bf(g);
            }
        }
    }
    __syncthreads();
    fx4 a2[4];
    #pragma unroll
    for (int a = 0; a < 4; ++a) a2[a] = (fx4){0.f, 0.f, 0.f, 0.f};
    #pragma unroll
    for (int kc = 0; kc < 16; ++kc) {
        bfx8 ha[4], wb;
        #pragma unroll
        for (int fm = 0; fm < 4; ++fm) {
            const int r = fm * 16 + (lane & 15);
            int byt = (r << 10) + (kc << 6) + kob;
            byt ^= (r & 7) << 4;
            ha[fm] = *(const bfx8*)(Hs + byt);
        }
        wb = *(const bfx8*)((const char*)W2p + ((kc * 8 + wid) << 10) + (lane << 4));
        #pragma unroll
        for (int fm = 0; fm < 4; ++fm)
            a2[fm] = __builtin_amdgcn_mfma_f32_16x16x32_bf16(ha[fm], wb, a2[fm], 0, 0, 0);
    }
    __syncthreads();   // Hs dead -> f32 overlay
    {
        const int col = wid * 16 + (lane & 15);
        const float bv = bias2[col];
        #pragma unroll
        for (int fm = 0; fm < 4; ++fm) {
            #pragma unroll
            for (int j = 0; j < 4; ++j) {
                const int r = fm * 16 + ((lane >> 4) << 2) + j;
                int byt = (r << 9) + (col << 2);
                byt ^= (r & 7) << 4;
                *(float*)(Hs + byt) = a2[fm][j] + bv;
            }
        }
    }
    __syncthreads();
    #pragma unroll
    for (int i = 0; i < 4; ++i) {
        const int bo = i * 8192 + tid * 16;
        const int r = bo >> 9;
        const int cb = bo & 511;
        int byt = bo ^ ((r & 7) << 4);
        float4 v = *(const float4*)(Hs + byt);
        const size_t o = (m0 + r) * 128 + (cb >> 2);
        const unsigned* rp = (const unsigned*)(resb + o);
        const unsigned r0 = rp[0], r1 = rp[1];
        v.x += bf2f((unsigned short)(r0 & 0xffffu));
        v.y += bf2f((unsigned short)(r0 >> 16));
        v.z += bf2f((unsigned short)(r1 & 0xffffu));
        v.w += bf2f((unsigned short)(r1 >> 16));
        *(float4*)(outp + o) = v;
    }
}

extern "C" void kernel_launch(void* const* d_in, const int* in_sizes, int n_in,
                              void* d_out, int out_size, void* d_ws, size_t ws_size,
                              hipStream_t stream) {
    const float* x          = (const float*)d_in[0];
    const float* dt         = (const float*)d_in[1];
    const float* ln_time_g  = (const float*)d_in[2];
    const float* ln_time_b  = (const float*)d_in[3];
    const float* ln_space_g = (const float*)d_in[4];
    const float* ln_space_b = (const float*)d_in[5];
    const float* ln_feat_g  = (const float*)d_in[6];
    const float* ln_feat_b  = (const float*)d_in[7];
    const float* ham_omega  = (const float*)d_in[8];
    const float* ham_bin    = (const float*)d_in[9];
    const float* ham_cr     = (const float*)d_in[10];
    const float* ham_ci     = (const float*)d_in[11];
    const float* ham_d      = (const float*)d_in[12];
    const float* cliff_wr   = (const float*)d_in[13];
    const float* cliff_wi   = (const float*)d_in[14];
    const float* cliff_br   = (const float*)d_in[15];
    const float* cliff_bi   = (const float*)d_in[16];
    const float* spec_ur    = (const float*)d_in[17];
    const float* spec_ui    = (const float*)d_in[18];
    const float* spec_vr    = (const float*)d_in[19];
    const float* spec_vi    = (const float*)d_in[20];
    const float* spec_decay = (const float*)d_in[21];
    const float* spec_omega = (const float*)d_in[22];
    const float* w1r        = (const float*)d_in[23];
    const float* w1i        = (const float*)d_in[24];
    const float* b1r        = (const float*)d_in[25];
    const float* b1i        = (const float*)d_in[26];
    const float* w2r        = (const float*)d_in[27];
    const float* w2i        = (const float*)d_in[28];
    const float* b2r        = (const float*)d_in[29];
    const float* b2i        = (const float*)d_in[30];

    float* out = (float*)d_out;
    const size_t NX = 8388608;               // B*T*H*W*C*2
    float* hout = out + NX;

    float* ws = (float*)d_ws;
    unsigned short* buf1b = (unsigned short*)ws;                 // 8388608 bf16
    unsigned short* xnb   = (unsigned short*)(ws + 4194304);     // 8388608 bf16
    unsigned short* xnb2  = (unsigned short*)(ws + 8388608);     // 8388608 bf16
    short* Bcv  = (short*)(ws + 12582912);                       // 147456 bf16
    short* W1p  = (short*)(ws + 12656640);                       // 65536 bf16
    short* W2p  = (short*)(ws + 12689408);                       // 65536 bf16
    float* biasc = ws + 12722176;                                // 128
    float* bias1 = ws + 12722304;                                // 512
    float* bias2 = ws + 12722816;                                // 128
    float* Kb    = ws + 12722944;                                // 4352
    float* Mb    = ws + 12727296;                                // 2176

    k_ts_pack<<<2128, 256, 0, stream>>>(x, dt, ln_time_g, ln_time_b,
                                        ham_omega, ham_bin, ham_cr, ham_ci,
                                        ham_d, ln_space_g, ln_space_b,
                                        buf1b, xnb, hout,
                                        cliff_wr, cliff_wi, cliff_br, cliff_bi,
                                        w1r, w1i, b1r, b1i, w2r, w2i, b2r, b2i,
                                        spec_ur, spec_ui, spec_vr, spec_vi,
                                        spec_decay, spec_omega,
                                        Bcv, W1p, W2p, biasc, bias1, bias2, Kb, Mb);
    k_conv<<<1024, 256, 0, stream>>>(xnb, Bcv, biasc, Kb, Mb, buf1b,
                                     ln_feat_g, ln_feat_b, xnb2);
    k_mlp<<<1024, 512, 0, stream>>>(xnb2, buf1b, W1p, W2p, bias1, bias2, out);
}